// Round 1
// baseline (772.662 us; speedup 1.0000x reference)
//
#include <hip/hip_runtime.h>

// GAT layer fused kernel, MI355X gfx950.
// Pipeline: count_k -> conv_h (f32->bf16) -> hnew_k (h@W^T+b, MFMA, stores
// row-major + transposed bf16) -> attn_k (flash-style fused att/softmax/PV).
// ws layout: [0,256): k (int); [256, +4MB): h_bf; +4MB: hnew_bf; +4MB: hnewT_bf.

typedef __attribute__((ext_vector_type(8))) short short8;   // 8 x bf16 frag (4 VGPR)
typedef __attribute__((ext_vector_type(4))) float f32x4;    // MFMA C/D frag

#define NN 8192
#define DD 256
#define NEGB -1.2983e16f   // -9e15 * log2(e), matches reference NEG_BIG in base-2 domain

__device__ __forceinline__ unsigned short f2bf(float f) {
  unsigned u = __builtin_bit_cast(unsigned, f);
  u += 0x7FFFu + ((u >> 16) & 1u);                 // RNE
  return (unsigned short)(u >> 16);
}
__device__ __forceinline__ float bf2f(unsigned short s) {
  unsigned u = ((unsigned)s) << 16;
  return __builtin_bit_cast(float, u);
}
__device__ __forceinline__ f32x4 mfma16(short8 a, short8 b, f32x4 c) {
  return __builtin_amdgcn_mfma_f32_16x16x32_bf16(a, b, c, 0, 0, 0);
}

// ---- k = sum(adj[:,0] != 0) ------------------------------------------------
__global__ __launch_bounds__(256) void count_k(const int* __restrict__ adj,
                                               int* __restrict__ kout) {
  __shared__ int red[256];
  int t = threadIdx.x, s = 0;
  for (int i = t; i < NN; i += 256) s += (adj[(size_t)i * NN] != 0);
  red[t] = s;
  __syncthreads();
  for (int off = 128; off; off >>= 1) {
    if (t < off) red[t] += red[t + off];
    __syncthreads();
  }
  if (t == 0) *kout = red[0];
}

// ---- h (f32) -> h_bf (bf16) ------------------------------------------------
__global__ __launch_bounds__(256) void conv_h(const float* __restrict__ h,
                                              unsigned short* __restrict__ hbf) {
  int i = (blockIdx.x * 256 + threadIdx.x) * 4;
  float4 v = *(const float4*)(h + i);
  ushort4 o;
  o.x = f2bf(v.x); o.y = f2bf(v.y); o.z = f2bf(v.z); o.w = f2bf(v.w);
  *(ushort4*)(hbf + i) = o;
}

// ---- h_new = h @ W^T + b, stored bf16 row-major (hnb) and transposed (hnT) -
__global__ __launch_bounds__(256) void hnew_k(const unsigned short* __restrict__ hbf,
                                              const float* __restrict__ W,
                                              const float* __restrict__ bias,
                                              unsigned short* __restrict__ hnb,
                                              unsigned short* __restrict__ hnT) {
  const int tid = threadIdx.x, w = tid >> 6, l = tid & 63, lr = l & 15, lg = l >> 4;
  const int row0 = blockIdx.x * 64 + w * 16;

  short8 a[8];
  const unsigned short* hp = hbf + (size_t)(row0 + lr) * DD;
#pragma unroll
  for (int kk = 0; kk < 8; ++kk) a[kk] = *(const short8*)(hp + kk * 32 + lg * 8);

  f32x4 acc[16];
#pragma unroll
  for (int nt = 0; nt < 16; ++nt) acc[nt] = (f32x4){0.f, 0.f, 0.f, 0.f};

#pragma unroll
  for (int kk = 0; kk < 8; ++kk) {
#pragma unroll
    for (int nt = 0; nt < 16; ++nt) {
      // B[k][n] = W[n][k]; lane: row n = nt*16+lr, k-run = kk*32 + lg*8 (+e)
      const float* wp = W + (size_t)(nt * 16 + lr) * DD + kk * 32 + lg * 8;
      float4 w0 = *(const float4*)wp;
      float4 w1 = *(const float4*)(wp + 4);
      short8 bf;
      bf[0] = (short)f2bf(w0.x); bf[1] = (short)f2bf(w0.y);
      bf[2] = (short)f2bf(w0.z); bf[3] = (short)f2bf(w0.w);
      bf[4] = (short)f2bf(w1.x); bf[5] = (short)f2bf(w1.y);
      bf[6] = (short)f2bf(w1.z); bf[7] = (short)f2bf(w1.w);
      acc[nt] = mfma16(a[kk], bf, acc[nt]);
    }
  }
#pragma unroll
  for (int nt = 0; nt < 16; ++nt) {
    const int col = nt * 16 + lr;
    const float bv = bias[col];
#pragma unroll
    for (int q = 0; q < 4; ++q) {
      const int row = row0 + lg * 4 + q;   // C/D: row = 4*(l>>4)+q, col = l&15
      unsigned short r16 = f2bf(acc[nt][q] + bv);
      hnb[(size_t)row * DD + col] = r16;
      hnT[(size_t)col * NN + row] = r16;
    }
  }
}

// ---- fused flash attention + epilogue --------------------------------------
// Block: 32 rows, 4 waves. Waves 0,1 -> rows [0,16),[16,32) on even j-tiles;
// waves 2,3 -> same rows on odd j-tiles. Combine halves via LDS at the end.
__global__ __launch_bounds__(256, 2) void attn_k(
    const unsigned short* __restrict__ hbf, const int* __restrict__ adj,
    const unsigned short* __restrict__ hnb, const unsigned short* __restrict__ hnT,
    const int* __restrict__ kptr, float* __restrict__ out) {
  __shared__ __align__(16) unsigned short sB[2][32][264];  // h cols tile [j][k], pad 528B stride
  __shared__ __align__(16) unsigned short sV[2][256][40];  // V^T tile [col][k], pad 80B stride
  __shared__ __align__(16) unsigned short sP[4][16][40];   // per-wave P transpose buffer
  __shared__ float sStat[64];                              // m[32], l[32] of odd half

  const int tid = threadIdx.x;
  const int w = tid >> 6, l = tid & 63, lr = l & 15, lg = l >> 4;
  const int half = w >> 1, rbase = (w & 1) * 16;
  const int i0 = blockIdx.x * 32;
  const int kid = *kptr;

  if (i0 + 32 <= kid) {  // whole block is identity rows: out = relu(h_new)
    const int row = i0 + (tid >> 3);
    const int c0 = (tid & 7) * 32;
#pragma unroll
    for (int s = 0; s < 4; ++s) {
      short8 hv = *(const short8*)(hnb + (size_t)row * DD + c0 + s * 8);
#pragma unroll
      for (int e = 0; e < 8; ++e)
        out[(size_t)row * DD + c0 + s * 8 + e] = fmaxf(bf2f((unsigned short)hv[e]), 0.f);
    }
    return;
  }

  // Q fragments hoisted for the whole j-loop (A layout: row=l&15, k-run=8*(l>>4))
  short8 qf[8];
  {
    const unsigned short* qp = hbf + (size_t)(i0 + rbase + lr) * DD;
#pragma unroll
    for (int kk = 0; kk < 8; ++kk) qf[kk] = *(const short8*)(qp + kk * 32 + lg * 8);
  }

  f32x4 Oacc[16];
#pragma unroll
  for (int nt = 0; nt < 16; ++nt) Oacc[nt] = (f32x4){0.f, 0.f, 0.f, 0.f};
  float m2[4] = {NEGB, NEGB, NEGB, NEGB};
  float lsum[4] = {0.f, 0.f, 0.f, 0.f};
  const float c1 = 0.09016844005556021f;  // log2(e)/sqrt(256): base-2 softmax domain

  const int th = tid & 127;  // thread index within this half (waves {0,1} / {2,3})

  for (int jt = half; jt < 256; jt += 2) {
    __syncthreads();
    {  // stage h-cols tile [32][256] bf16, linear copy, coalesced
      const unsigned short* src = hbf + (size_t)jt * 32 * DD;
#pragma unroll
      for (int s = 0; s < 8; ++s) {
        int ch = s * 128 + th, r = ch >> 5, c = ch & 31;
        *(uint4*)(&sB[half][r][c * 8]) = *(const uint4*)(src + r * DD + c * 8);
      }
      // stage V^T tile [256][32] bf16 from pre-transposed hnT, linear copy
#pragma unroll
      for (int s = 0; s < 8; ++s) {
        int ch = s * 128 + th, col = ch >> 2, s4 = ch & 3;
        *(uint4*)(&sV[half][col][s4 * 8]) =
            *(const uint4*)(hnT + (size_t)col * NN + jt * 32 + s4 * 8);
      }
    }
    // adj mask loads (HBM stream) — issue alongside staging
    int av[2][4];
#pragma unroll
    for (int nt = 0; nt < 2; ++nt)
#pragma unroll
      for (int q = 0; q < 4; ++q)
        av[nt][q] = adj[(size_t)(i0 + rbase + lg * 4 + q) * NN + jt * 32 + nt * 16 + lr];
    __syncthreads();

    // S = h_rows . h_cols^T  (two 16x16 n-tiles, K=256)
    f32x4 Sacc[2];
    Sacc[0] = (f32x4){0.f, 0.f, 0.f, 0.f};
    Sacc[1] = (f32x4){0.f, 0.f, 0.f, 0.f};
#pragma unroll
    for (int kk = 0; kk < 8; ++kk) {
#pragma unroll
      for (int nt = 0; nt < 2; ++nt) {
        short8 bf = *(const short8*)(&sB[half][nt * 16 + lr][kk * 32 + lg * 8]);
        Sacc[nt] = mfma16(qf[kk], bf, Sacc[nt]);
      }
    }

    // masked online softmax (base-2). Masked -> NEGB, matching reference NEG_BIG.
    float sv[2][4], mt[4];
#pragma unroll
    for (int q = 0; q < 4; ++q) {
      sv[0][q] = av[0][q] ? Sacc[0][q] * c1 : NEGB;
      sv[1][q] = av[1][q] ? Sacc[1][q] * c1 : NEGB;
      mt[q] = fmaxf(sv[0][q], sv[1][q]);
    }
#pragma unroll
    for (int q = 0; q < 4; ++q)
#pragma unroll
      for (int off = 1; off < 16; off <<= 1)
        mt[q] = fmaxf(mt[q], __shfl_xor(mt[q], off));

    float fac[4], rs[4];
#pragma unroll
    for (int q = 0; q < 4; ++q) {
      float mn = fmaxf(m2[q], mt[q]);
      fac[q] = __builtin_amdgcn_exp2f(m2[q] - mn);
      float p0 = __builtin_amdgcn_exp2f(sv[0][q] - mn);  // masked: exp2(-1.3e16)=0
      float p1 = __builtin_amdgcn_exp2f(sv[1][q] - mn);
      sv[0][q] = p0; sv[1][q] = p1;
      rs[q] = p0 + p1;
      m2[q] = mn;
    }
#pragma unroll
    for (int q = 0; q < 4; ++q) {
#pragma unroll
      for (int off = 1; off < 16; off <<= 1) rs[q] += __shfl_xor(rs[q], off);
      lsum[q] = lsum[q] * fac[q] + rs[q];
    }
#pragma unroll
    for (int nt = 0; nt < 16; ++nt)
#pragma unroll
      for (int q = 0; q < 4; ++q) Oacc[nt][q] *= fac[q];

    // P (C layout) -> LDS -> re-read in A layout for PV
#pragma unroll
    for (int nt = 0; nt < 2; ++nt)
#pragma unroll
      for (int q = 0; q < 4; ++q)
        sP[w][lg * 4 + q][nt * 16 + lr] = f2bf(sv[nt][q]);
    short8 pa = *(const short8*)(&sP[w][lr][lg * 8]);  // per-wave buffer, no barrier needed
#pragma unroll
    for (int cnt = 0; cnt < 16; ++cnt) {
      short8 vf = *(const short8*)(&sV[half][cnt * 16 + lr][lg * 8]);
      Oacc[cnt] = mfma16(pa, vf, Oacc[cnt]);
    }
  }

  // combine odd half into even half via LDS
  __syncthreads();
  float* Ocomb = (float*)&sB[0][0][0];  // [32][260] f32, reuses staging LDS
  if (half == 1) {
#pragma unroll
    for (int q = 0; q < 4; ++q) {
      int r = rbase + lg * 4 + q;
      sStat[r] = m2[q];
      sStat[32 + r] = lsum[q];
    }
#pragma unroll
    for (int cnt = 0; cnt < 16; ++cnt)
#pragma unroll
      for (int q = 0; q < 4; ++q)
        Ocomb[(rbase + lg * 4 + q) * 260 + cnt * 16 + lr] = Oacc[cnt][q];
  }
  __syncthreads();
  if (half == 0) {
    float fE[4], fO[4], inv[4];
#pragma unroll
    for (int q = 0; q < 4; ++q) {
      int r = rbase + lg * 4 + q;
      float mo = sStat[r], lo = sStat[32 + r];
      float ms = fmaxf(m2[q], mo);
      fE[q] = __builtin_amdgcn_exp2f(m2[q] - ms);
      fO[q] = __builtin_amdgcn_exp2f(mo - ms);
      inv[q] = 0.5f / (lsum[q] * fE[q] + lo * fO[q]);
    }
#pragma unroll
    for (int cnt = 0; cnt < 16; ++cnt) {
#pragma unroll
      for (int q = 0; q < 4; ++q) {
        int r = rbase + lg * 4 + q;
        int row = i0 + r, col = cnt * 16 + lr;
        float Ostar = Oacc[cnt][q] * fE[q] + Ocomb[r * 260 + col] * fO[q];
        float v = bf2f(hnb[(size_t)row * DD + col]);
        float res = Ostar * inv[q] + 0.5f * v;   // 0.5*(P.V)/l + 0.5*v_self
        if (row < kid) res = v;                  // identity-row override
        out[(size_t)row * DD + col] = fmaxf(res, 0.f);
      }
    }
  }
}

extern "C" void kernel_launch(void* const* d_in, const int* in_sizes, int n_in,
                              void* d_out, int out_size, void* d_ws, size_t ws_size,
                              hipStream_t stream) {
  const float* h = (const float*)d_in[0];
  const int* adj = (const int*)d_in[1];
  const float* W = (const float*)d_in[2];
  const float* b = (const float*)d_in[3];
  float* out = (float*)d_out;

  char* ws = (char*)d_ws;
  int* kbuf = (int*)ws;
  unsigned short* hbf = (unsigned short*)(ws + 256);
  unsigned short* hnb = (unsigned short*)(ws + 256 + (size_t)NN * DD * 2);
  unsigned short* hnT = (unsigned short*)(ws + 256 + (size_t)NN * DD * 4);
  // ws required: 256 + 3 * 4MB = ~12.6 MB

  hipLaunchKernelGGL(count_k, dim3(1), dim3(256), 0, stream, adj, kbuf);
  hipLaunchKernelGGL(conv_h, dim3((NN * DD / 4) / 256), dim3(256), 0, stream, h, hbf);
  hipLaunchKernelGGL(hnew_k, dim3(NN / 64), dim3(256), 0, stream, hbf, W, b, hnb, hnT);
  hipLaunchKernelGGL(attn_k, dim3(NN / 32), dim3(256), 0, stream, hbf, adj, hnb, hnT, kbuf, out);
}

// Round 2
// 295.295 us; speedup vs baseline: 2.6166x; 2.6166x over previous
//
#include <hip/hip_runtime.h>

// GAT layer fused, MI355X gfx950 — v2: split-j flash + barrier-free frag loop.
// Pipeline: count_k | conv_h -> hnew_k -> pack_qf/pack_vf/pack_wf -> attn_part
//           (grid 256 row-tiles x S chunks, partial m/l/O to ws) -> comb_k.

typedef __attribute__((ext_vector_type(8))) short short8;   // 8 x bf16 (4 VGPR)
typedef __attribute__((ext_vector_type(4))) float f32x4;    // MFMA C/D frag

#define NN 8192
#define DD 256
#define NEGB -1.2983e16f  // -9e15 * log2(e): NEG_BIG in base-2 softmax domain

__device__ __forceinline__ unsigned short f2bf(float f) {
  unsigned u = __builtin_bit_cast(unsigned, f);
  u += 0x7FFFu + ((u >> 16) & 1u);  // RNE
  return (unsigned short)(u >> 16);
}
__device__ __forceinline__ float bf2f(unsigned short s) {
  unsigned u = ((unsigned)s) << 16;
  return __builtin_bit_cast(float, u);
}
__device__ __forceinline__ f32x4 mfma16(short8 a, short8 b, f32x4 c) {
  return __builtin_amdgcn_mfma_f32_16x16x32_bf16(a, b, c, 0, 0, 0);
}

// ---- k = sum(adj[:,0] != 0): 32 blocks + atomic --------------------------
__global__ __launch_bounds__(256) void count_k(const int* __restrict__ adj,
                                               int* __restrict__ kout) {
  __shared__ int red[256];
  int gid = blockIdx.x * 256 + threadIdx.x;
  red[threadIdx.x] = (adj[(size_t)gid * NN] != 0);
  __syncthreads();
  for (int off = 128; off; off >>= 1) {
    if (threadIdx.x < off) red[threadIdx.x] += red[threadIdx.x + off];
    __syncthreads();
  }
  if (threadIdx.x == 0) atomicAdd(kout, red[0]);
}

// ---- h (f32) -> h_bf (bf16) -----------------------------------------------
__global__ __launch_bounds__(256) void conv_h(const float* __restrict__ h,
                                              unsigned short* __restrict__ hbf) {
  int i = (blockIdx.x * 256 + threadIdx.x) * 4;
  float4 v = *(const float4*)(h + i);
  ushort4 o;
  o.x = f2bf(v.x); o.y = f2bf(v.y); o.z = f2bf(v.z); o.w = f2bf(v.w);
  *(ushort4*)(hbf + i) = o;
}

// ---- W (f32 [256][256]) -> bf16 B-frags: frag(n16,kk) lane l --------------
__global__ __launch_bounds__(256) void pack_wf(const float* __restrict__ W,
                                               unsigned short* __restrict__ Wf) {
  int gid = blockIdx.x * 256 + threadIdx.x;  // 8192 total
  int l = gid & 63, f = gid >> 6, n16 = f >> 3, kk = f & 7;
  int lr = l & 15, lg = l >> 4;
  const float* src = W + (size_t)(n16 * 16 + lr) * DD + kk * 32 + lg * 8;
  float4 w0 = *(const float4*)src, w1 = *(const float4*)(src + 4);
  short8 o;
  o[0] = (short)f2bf(w0.x); o[1] = (short)f2bf(w0.y);
  o[2] = (short)f2bf(w0.z); o[3] = (short)f2bf(w0.w);
  o[4] = (short)f2bf(w1.x); o[5] = (short)f2bf(w1.y);
  o[6] = (short)f2bf(w1.z); o[7] = (short)f2bf(w1.w);
  *(short8*)(Wf + (size_t)gid * 8) = o;
}

// ---- h_new = h @ W^T + b -> hnb (row-major bf16) + hnT (transposed bf16) --
__global__ __launch_bounds__(256) void hnew_k(const unsigned short* __restrict__ hbf,
                                              const unsigned short* __restrict__ Wf,
                                              const float* __restrict__ bias,
                                              unsigned short* __restrict__ hnb,
                                              unsigned short* __restrict__ hnT) {
  const int tid = threadIdx.x, w = tid >> 6, l = tid & 63, lr = l & 15, lg = l >> 4;
  const int row0 = blockIdx.x * 64 + w * 16;

  short8 a[8];
  const unsigned short* hp = hbf + (size_t)(row0 + lr) * DD;
#pragma unroll
  for (int kk = 0; kk < 8; ++kk) a[kk] = *(const short8*)(hp + kk * 32 + lg * 8);

  f32x4 acc[16];
#pragma unroll
  for (int nt = 0; nt < 16; ++nt) acc[nt] = (f32x4){0.f, 0.f, 0.f, 0.f};

#pragma unroll
  for (int kk = 0; kk < 8; ++kk)
#pragma unroll
    for (int nt = 0; nt < 16; ++nt) {
      short8 bf = *(const short8*)(Wf + ((size_t)(nt * 8 + kk) * 64 + l) * 8);
      acc[nt] = mfma16(a[kk], bf, acc[nt]);
    }
#pragma unroll
  for (int nt = 0; nt < 16; ++nt) {
    const int col = nt * 16 + lr;
    const float bv = bias[col];
#pragma unroll
    for (int q = 0; q < 4; ++q) {
      const int row = row0 + lg * 4 + q;
      unsigned short r16 = f2bf(acc[nt][q] + bv);
      hnb[(size_t)row * DD + col] = r16;
      hnT[(size_t)col * NN + row] = r16;
    }
  }
}

// ---- pack QK B-frags: hQf frag(j16 0..512, kk 0..8) lane l ----------------
__global__ __launch_bounds__(256) void pack_qf(const unsigned short* __restrict__ hbf,
                                               unsigned short* __restrict__ hQf) {
  int gid = blockIdx.x * 256 + threadIdx.x;  // 262144 total
  int l = gid & 63, f = gid >> 6, j16 = f >> 3, kk = f & 7;
  int lr = l & 15, lg = l >> 4;
  *(short8*)(hQf + (size_t)gid * 8) =
      *(const short8*)(hbf + (size_t)(j16 * 16 + lr) * DD + kk * 32 + lg * 8);
}

// ---- pack PV B-frags: hnV frag(jt 0..256, cnt 0..16) lane l ---------------
__global__ __launch_bounds__(256) void pack_vf(const unsigned short* __restrict__ hnT,
                                               unsigned short* __restrict__ hnV) {
  int gid = blockIdx.x * 256 + threadIdx.x;  // 262144 total
  int l = gid & 63, f = gid >> 6, jt = f >> 4, cnt = f & 15;
  int lr = l & 15, lg = l >> 4;
  *(short8*)(hnV + (size_t)gid * 8) =
      *(const short8*)(hnT + (size_t)(cnt * 16 + lr) * NN + jt * 32 + lg * 8);
}

// ---- flash attention partials: block = (row-tile i0, chunk c), 4 waves ----
// wave w: rows [i0+(w&1)*16, +16), j-tile parity w>>1 within chunk.
// No barriers in the j-loop; per-wave sP exchange; end-of-block parity merge.
__global__ __launch_bounds__(256) void attn_part(
    const unsigned short* __restrict__ hbf, const unsigned short* __restrict__ hQf,
    const unsigned short* __restrict__ hnV, const int* __restrict__ adj,
    const int* __restrict__ kptr, float* __restrict__ pm, float* __restrict__ pl,
    float* __restrict__ pO, int T) {
  __shared__ __align__(16) unsigned short sP[4][16][40];  // per-wave P transpose
  __shared__ float Ocomb[32][260];                        // parity-1 O at end
  __shared__ float sStat[64];                             // parity-1 m,l at end

  const int tid = threadIdx.x;
  const int w = tid >> 6, l = tid & 63, lr = l & 15, lg = l >> 4;
  const int rsub = (w & 1) * 16, par = w >> 1;
  const int i0 = blockIdx.x * 32, c = blockIdx.y;
  const int kid = *kptr;

  if (i0 + 32 <= kid) return;  // pure identity tile: comb_k handles rows < k

  // Q A-frags (row = lr, k-run = kk*32 + lg*8)
  short8 qf[8];
  {
    const unsigned short* qp = hbf + (size_t)(i0 + rsub + lr) * DD;
#pragma unroll
    for (int kk = 0; kk < 8; ++kk) qf[kk] = *(const short8*)(qp + kk * 32 + lg * 8);
  }

  f32x4 Oacc[16];
#pragma unroll
  for (int nt = 0; nt < 16; ++nt) Oacc[nt] = (f32x4){0.f, 0.f, 0.f, 0.f};
  float m2[4] = {NEGB, NEGB, NEGB, NEGB};
  float lsum[4] = {0.f, 0.f, 0.f, 0.f};
  const float c1 = 0.09016844005556021f;  // log2(e)/sqrt(256)

  size_t arow[4];
#pragma unroll
  for (int q = 0; q < 4; ++q) arow[q] = (size_t)(i0 + rsub + lg * 4 + q) * NN;

  const int jend = (c + 1) * T;
  int jt = c * T + par;
  int av[2][4], avn[2][4];
#pragma unroll
  for (int nt = 0; nt < 2; ++nt)
#pragma unroll
    for (int q = 0; q < 4; ++q) av[nt][q] = adj[arow[q] + jt * 32 + nt * 16 + lr];

  for (; jt < jend; jt += 2) {
    if (jt + 2 < jend) {  // adj prefetch one tile ahead (HBM latency cover)
#pragma unroll
      for (int nt = 0; nt < 2; ++nt)
#pragma unroll
        for (int q = 0; q < 4; ++q)
          avn[nt][q] = adj[arow[q] + (jt + 2) * 32 + nt * 16 + lr];
    }

    // S = Q . hcols^T over K=256, coalesced B-frags from hQf
    f32x4 Sacc[2];
    Sacc[0] = (f32x4){0.f, 0.f, 0.f, 0.f};
    Sacc[1] = (f32x4){0.f, 0.f, 0.f, 0.f};
#pragma unroll
    for (int kk = 0; kk < 8; ++kk)
#pragma unroll
      for (int nt = 0; nt < 2; ++nt) {
        short8 bf = *(const short8*)(hQf + ((size_t)((jt * 2 + nt) * 8 + kk) * 64 + l) * 8);
        Sacc[nt] = mfma16(qf[kk], bf, Sacc[nt]);
      }

    // masked online softmax (base-2)
    float sv[2][4], mt[4];
#pragma unroll
    for (int q = 0; q < 4; ++q) {
      sv[0][q] = av[0][q] ? Sacc[0][q] * c1 : NEGB;
      sv[1][q] = av[1][q] ? Sacc[1][q] * c1 : NEGB;
      mt[q] = fmaxf(sv[0][q], sv[1][q]);
    }
#pragma unroll
    for (int q = 0; q < 4; ++q)
#pragma unroll
      for (int off = 1; off < 16; off <<= 1)
        mt[q] = fmaxf(mt[q], __shfl_xor(mt[q], off));

    float fac[4], rs[4];
#pragma unroll
    for (int q = 0; q < 4; ++q) {
      float mn = fmaxf(m2[q], mt[q]);
      fac[q] = __builtin_amdgcn_exp2f(m2[q] - mn);
      float p0 = __builtin_amdgcn_exp2f(sv[0][q] - mn);
      float p1 = __builtin_amdgcn_exp2f(sv[1][q] - mn);
      sv[0][q] = p0; sv[1][q] = p1;
      rs[q] = p0 + p1;
      m2[q] = mn;
    }
#pragma unroll
    for (int q = 0; q < 4; ++q) {
#pragma unroll
      for (int off = 1; off < 16; off <<= 1) rs[q] += __shfl_xor(rs[q], off);
      lsum[q] = lsum[q] * fac[q] + rs[q];
    }
#pragma unroll
    for (int nt = 0; nt < 16; ++nt)
#pragma unroll
      for (int q = 0; q < 4; ++q) Oacc[nt][q] *= fac[q];

    // P (C layout) -> per-wave LDS -> A layout
#pragma unroll
    for (int nt = 0; nt < 2; ++nt)
#pragma unroll
      for (int q = 0; q < 4; ++q)
        sP[w][lg * 4 + q][nt * 16 + lr] = f2bf(sv[nt][q]);
    short8 pa = *(const short8*)(&sP[w][lr][lg * 8]);

    // PV with coalesced V-frags from hnV
#pragma unroll
    for (int cnt = 0; cnt < 16; ++cnt) {
      short8 vf = *(const short8*)(hnV + ((size_t)(jt * 16 + cnt) * 64 + l) * 8);
      Oacc[cnt] = mfma16(pa, vf, Oacc[cnt]);
    }

#pragma unroll
    for (int nt = 0; nt < 2; ++nt)
#pragma unroll
      for (int q = 0; q < 4; ++q) av[nt][q] = avn[nt][q];
  }

  // merge parity 1 into parity 0, write chunk partial
  __syncthreads();
  if (par == 1) {
#pragma unroll
    for (int q = 0; q < 4; ++q) {
      int r = rsub + lg * 4 + q;
      if (lr == 0) { sStat[r] = m2[q]; sStat[32 + r] = lsum[q]; }
    }
#pragma unroll
    for (int cnt = 0; cnt < 16; ++cnt)
#pragma unroll
      for (int q = 0; q < 4; ++q)
        Ocomb[rsub + lg * 4 + q][cnt * 16 + lr] = Oacc[cnt][q];
  }
  __syncthreads();
  if (par == 0) {
    float fE[4], fO[4], mC[4], lC[4];
#pragma unroll
    for (int q = 0; q < 4; ++q) {
      int r = rsub + lg * 4 + q;
      float mo = sStat[r], lo = sStat[32 + r];
      float ms = fmaxf(m2[q], mo);
      fE[q] = __builtin_amdgcn_exp2f(m2[q] - ms);
      fO[q] = __builtin_amdgcn_exp2f(mo - ms);
      mC[q] = ms;
      lC[q] = lsum[q] * fE[q] + lo * fO[q];
      if (lr == 0) {
        pm[(size_t)c * NN + i0 + r] = ms;
        pl[(size_t)c * NN + i0 + r] = lC[q];
      }
    }
#pragma unroll
    for (int cnt = 0; cnt < 16; ++cnt)
#pragma unroll
      for (int q = 0; q < 4; ++q) {
        int r = rsub + lg * 4 + q;
        pO[((size_t)c * NN + i0 + r) * DD + cnt * 16 + lr] =
            Oacc[cnt][q] * fE[q] + Ocomb[r][cnt * 16 + lr] * fO[q];
      }
  }
}

// ---- combine chunks + epilogue: one block per row ------------------------
__global__ __launch_bounds__(256) void comb_k(const float* __restrict__ pm,
                                              const float* __restrict__ pl,
                                              const float* __restrict__ pO,
                                              const unsigned short* __restrict__ hnb,
                                              const int* __restrict__ kptr,
                                              float* __restrict__ out, int S) {
  const int row = blockIdx.x, col = threadIdx.x;
  const int kid = *kptr;
  float v = bf2f(hnb[(size_t)row * DD + col]);
  float res;
  if (row < kid) {
    res = v;
  } else {
    float M = NEGB;
    for (int cc = 0; cc < S; ++cc) M = fmaxf(M, pm[(size_t)cc * NN + row]);
    float L = 0.f, acc = 0.f;
    for (int cc = 0; cc < S; ++cc) {
      float f = __builtin_amdgcn_exp2f(pm[(size_t)cc * NN + row] - M);
      L += pl[(size_t)cc * NN + row] * f;
      acc += pO[((size_t)cc * NN + row) * DD + col] * f;
    }
    res = acc * (0.5f / L) + 0.5f * v;
  }
  out[(size_t)row * DD + col] = fmaxf(res, 0.f);
}

extern "C" void kernel_launch(void* const* d_in, const int* in_sizes, int n_in,
                              void* d_out, int out_size, void* d_ws, size_t ws_size,
                              hipStream_t stream) {
  const float* h = (const float*)d_in[0];
  const int* adj = (const int*)d_in[1];
  const float* W = (const float*)d_in[2];
  const float* b = (const float*)d_in[3];
  float* out = (float*)d_out;

  char* ws = (char*)d_ws;
  const size_t MB4 = (size_t)NN * DD * 2;  // 4 MiB (bf16 8192x256)
  int* kbuf = (int*)ws;
  unsigned short* hbf = (unsigned short*)(ws + 256);
  unsigned short* hnb = (unsigned short*)(ws + 256 + MB4);
  unsigned short* hnT = (unsigned short*)(ws + 256 + 2 * MB4);
  unsigned short* hQf = (unsigned short*)(ws + 256 + 3 * MB4);
  unsigned short* hnV = (unsigned short*)(ws + 256 + 4 * MB4);
  unsigned short* Wf  = (unsigned short*)(ws + 256 + 5 * MB4);  // 128 KiB
  float* pm = (float*)(ws + 256 + 5 * MB4 + (256 << 10));
  float* pl = pm + 8 * (size_t)NN;
  float* pO = pl + 8 * (size_t)NN;

  size_t fixed = 256 + 5 * MB4 + (256 << 10) + 16 * (size_t)NN * 4;
  int S = 8;
  while (S > 1 && fixed + (size_t)S * NN * DD * 4 > ws_size) S >>= 1;
  const int T = 256 / S;  // j-tiles per chunk

  hipMemsetAsync(kbuf, 0, 4, stream);
  hipLaunchKernelGGL(count_k, dim3(32), dim3(256), 0, stream, adj, kbuf);
  hipLaunchKernelGGL(conv_h, dim3((NN * DD / 4) / 256), dim3(256), 0, stream, h, hbf);
  hipLaunchKernelGGL(pack_wf, dim3(32), dim3(256), 0, stream, W, Wf);
  hipLaunchKernelGGL(hnew_k, dim3(NN / 64), dim3(256), 0, stream, hbf, Wf, b, hnb, hnT);
  hipLaunchKernelGGL(pack_qf, dim3(1024), dim3(256), 0, stream, hbf, hQf);
  hipLaunchKernelGGL(pack_vf, dim3(1024), dim3(256), 0, stream, hnT, hnV);
  hipLaunchKernelGGL(attn_part, dim3(NN / 32, S), dim3(256), 0, stream,
                     hbf, hQf, hnV, adj, kbuf, pm, pl, pO, T);
  hipLaunchKernelGGL(comb_k, dim3(NN), dim3(256), 0, stream, pm, pl, pO, hnb, kbuf, out, S);
}